// Round 2
// baseline (2255.889 us; speedup 1.0000x reference)
//
#include <hip/hip_runtime.h>
#include <math.h>

#define B_LEN 1024
#define T_LEN 256
#define HST 36   // hid_sh leading stride: banks (4*i8+h)%32 distinct over i8 -> conflict-free

__device__ __forceinline__ float fast_rcp(float x) { return __builtin_amdgcn_rcpf(x); }
__device__ __forceinline__ float fast_tanh(float x) {
    float e = __expf(2.0f * x);
    return 1.0f - 2.0f * fast_rcp(e + 1.0f);
}
__device__ __forceinline__ float softplus_f(float x) {
    return (x > 20.0f) ? x : log1pf(expf(x));
}

// One wave (64 lanes) per TWO batch elements (q = 0,1), chains interleaved for ILP.
// Lane layouts:
//   (i8,j8)  = (lane>>3, lane&7)   : 8x8 matrix entry (P, chol8, P_pred) -- per-q loop
//   (h32,p2) = (lane&31, lane>>5)  : layer-1 (hidden unit, sigma parity) -- per-q loop
//   (sy,m4)  = (lane>>2, lane&3)   : y-side all-lane layout               -- per-q loop
//   Sy/chol4 : lanes 0..31, qS=lane>>4, idx16=lane&15, (syS,m4S)=(idx16>>2, idx16&3)
//   Pxy/T1   : all 64, qP=lane>>5, idxP=lane&31, (iiP,mmP)=(idxP>>2, idxP&3)
//   K/x_new  : lanes 0..15, qK=lane>>3, rowK=lane&7
__global__ __launch_bounds__(64)
void ukf_kernel(const float* __restrict__ X0, const float* __restrict__ U,
                const float* __restrict__ Y,  const float* __restrict__ W1,
                const float* __restrict__ B1, const float* __restrict__ W2,
                const float* __restrict__ B2, const float* __restrict__ HM,
                const float* __restrict__ LQ, const float* __restrict__ LR,
                const float* __restrict__ LP0, float* __restrict__ out)
{
    const int b0   = blockIdx.x * 2;
    const int lane = threadIdx.x;
    const int i8   = lane >> 3;
    const int j8   = lane & 7;
    const int h32  = lane & 31;
    const int p2   = lane >> 5;
    const int m4   = lane & 3;
    const int sy   = lane >> 2;
    const int qS = (lane >> 4) & 1, idx16 = lane & 15, syS = idx16 >> 2, m4S = idx16 & 3;
    const int gbase = lane & 16;                 // chol4 group shuffle base
    const int qP = lane >> 5, idxP = lane & 31, iiP = idxP >> 2, mmP = idxP & 3;
    const int qK = lane >> 3, rowK = lane & 7;   // valid for lane<16

    __shared__ __align__(16) float u_sh[2][T_LEN * 2];
    __shared__ __align__(16) float y_sh[2][T_LEN * 4];
    __shared__ __align__(16) float pts_sh[2][17 * 8];
    __shared__ __align__(16) float hid_sh[2][17 * HST];
    __shared__ __align__(16) float pf_sh[2][17 * 8];   // pts_f, then dx in place
    __shared__ __align__(16) float yp_sh[2][17 * 4];   // dy
    __shared__ float x_sh[2][8];
    __shared__ float xp_sh[2][8];
    __shared__ float ypred_sh[2][4];
    __shared__ float Sy_sh[2][16];
    __shared__ float L4_sh[2][16];
    __shared__ float Pxy_sh[2][32];
    __shared__ float K_sh[2][32];
    __shared__ float T1_sh[2][32];

    // ---- one-time staging ----
    for (int k = lane; k < T_LEN * 2; k += 64) {
        u_sh[0][k] = U[(size_t)b0 * (T_LEN * 2) + k];
        u_sh[1][k] = U[(size_t)(b0 + 1) * (T_LEN * 2) + k];
    }
    for (int k = lane; k < T_LEN * 4; k += 64) {
        y_sh[0][k] = Y[(size_t)b0 * (T_LEN * 4) + k];
        y_sh[1][k] = Y[(size_t)(b0 + 1) * (T_LEN * 4) + k];
    }

    float w1r[10];
    #pragma unroll
    for (int d = 0; d < 10; ++d) w1r[d] = W1[d * 32 + h32];
    const float b1r = B1[h32];
    float w2r[32];
    #pragma unroll
    for (int h = 0; h < 32; ++h) w2r[h] = W2[h * 8 + j8];
    const float b2r = B2[j8];
    float hmr[8];
    #pragma unroll
    for (int d = 0; d < 8; ++d) hmr[d] = HM[m4 * 8 + d];

    const float qdiag  = softplus_f(LQ[i8]);
    const float rdiagS = softplus_f(LR[m4S]);

    size_t Xb[2], Pb[2], qb[2], rb[2];
    #pragma unroll
    for (int q = 0; q < 2; ++q) {
        const size_t b = (size_t)(b0 + q);
        Xb[q] = b * T_LEN * 8;
        Pb[q] = (size_t)B_LEN * T_LEN * 8  + b * T_LEN * 64;
        qb[q] = (size_t)B_LEN * T_LEN * 72 + b * T_LEN;
        rb[q] = (size_t)B_LEN * T_LEN * 73 + b * T_LEN;
    }

    // ---- initial state / t=0 outputs ----
    float P[2];
    P[0] = P[1] = (i8 == j8) ? softplus_f(LP0[i8]) : 0.0f;
    if (lane < 16) x_sh[lane >> 3][lane & 7] = X0[(size_t)(b0 + (lane >> 3)) * 8 + (lane & 7)];
    #pragma unroll
    for (int q = 0; q < 2; ++q) {
        if (lane < 8) out[Xb[q] + lane] = X0[(size_t)(b0 + q) * 8 + lane];
        out[Pb[q] + lane] = P[q];
        if (lane == 0) { out[qb[q]] = 0.0f; out[rb[q]] = 0.0f; }
    }
    __syncthreads();

    for (int t = 1; t < T_LEN; ++t) {
        // ===== chol8(8*P + jitter), both batches interleaved (shfl, in-register)
        float a0 = 8.0f * P[0] + ((i8 == j8) ? 1e-4f : 0.0f);
        float a1 = 8.0f * P[1] + ((i8 == j8) ? 1e-4f : 0.0f);
        #pragma unroll
        for (int j = 0; j < 8; ++j) {
            float d0 = __shfl(a0, j * 9), d1 = __shfl(a1, j * 9);
            float s0 = sqrtf(d0),         s1 = sqrtf(d1);
            float r0 = fast_rcp(s0),      r1 = fast_rcp(s1);
            if (j8 == j) { a0 = (i8 == j) ? s0 : a0 * r0; a1 = (i8 == j) ? s1 : a1 * r1; }
            float ci0 = __shfl(a0, i8 * 8 + j), ci1 = __shfl(a1, i8 * 8 + j);
            float cj0 = __shfl(a0, j8 * 8 + j), cj1 = __shfl(a1, j8 * 8 + j);
            if (i8 > j && j8 > j) { a0 -= ci0 * cj0; a1 -= ci1 * cj1; }
        }
        const float Lx0 = (j8 <= i8) ? a0 : 0.0f;
        const float Lx1 = (j8 <= i8) ? a1 : 0.0f;

        // ===== sigma points -> LDS
        const float xi0 = x_sh[0][i8], xi1 = x_sh[1][i8];
        if (j8 == 0) { pts_sh[0][i8] = xi0; pts_sh[1][i8] = xi1; }
        pts_sh[0][(1 + j8) * 8 + i8] = xi0 + Lx0;
        pts_sh[1][(1 + j8) * 8 + i8] = xi1 + Lx1;
        pts_sh[0][(9 + j8) * 8 + i8] = xi0 - Lx0;
        pts_sh[1][(9 + j8) * 8 + i8] = xi1 - Lx1;
        __syncthreads();

        // ===== layer 1: hidden = tanh([pts;u] W1 + b1)
        const float ub0 = b1r + u_sh[0][(t - 1) * 2] * w1r[8] + u_sh[0][(t - 1) * 2 + 1] * w1r[9];
        const float ub1 = b1r + u_sh[1][(t - 1) * 2] * w1r[8] + u_sh[1][(t - 1) * 2 + 1] * w1r[9];
        #pragma unroll
        for (int s0_ = 0; s0_ < 9; ++s0_) {
            int s = 2 * s0_ + p2;
            if (s < 17) {
                const float4 pa0 = *(const float4*)&pts_sh[0][s * 8];
                const float4 pb0 = *(const float4*)&pts_sh[0][s * 8 + 4];
                const float4 pa1 = *(const float4*)&pts_sh[1][s * 8];
                const float4 pb1 = *(const float4*)&pts_sh[1][s * 8 + 4];
                float acc0 = ub0
                    + pa0.x * w1r[0] + pa0.y * w1r[1] + pa0.z * w1r[2] + pa0.w * w1r[3]
                    + pb0.x * w1r[4] + pb0.y * w1r[5] + pb0.z * w1r[6] + pb0.w * w1r[7];
                float acc1 = ub1
                    + pa1.x * w1r[0] + pa1.y * w1r[1] + pa1.z * w1r[2] + pa1.w * w1r[3]
                    + pb1.x * w1r[4] + pb1.y * w1r[5] + pb1.z * w1r[6] + pb1.w * w1r[7];
                hid_sh[0][s * HST + h32] = fast_tanh(acc0);
                hid_sh[1][s * HST + h32] = fast_tanh(acc1);
            }
        }
        __syncthreads();

        // ===== layer 2: pts_f = pts + hidden W2 + b2
        float pf0[2], pf1[2], pf2[2] = {0.0f, 0.0f};
        #pragma unroll
        for (int q = 0; q < 2; ++q) {
            float acc = b2r;
            #pragma unroll
            for (int h = 0; h < 32; h += 4) {
                const float4 hv = *(const float4*)&hid_sh[q][i8 * HST + h];
                acc += hv.x * w2r[h] + hv.y * w2r[h + 1] + hv.z * w2r[h + 2] + hv.w * w2r[h + 3];
            }
            pf0[q] = pts_sh[q][i8 * 8 + j8] + acc;
            pf_sh[q][i8 * 8 + j8] = pf0[q];
        }
        #pragma unroll
        for (int q = 0; q < 2; ++q) {
            float acc = b2r;
            #pragma unroll
            for (int h = 0; h < 32; h += 4) {
                const float4 hv = *(const float4*)&hid_sh[q][(8 + i8) * HST + h];
                acc += hv.x * w2r[h] + hv.y * w2r[h + 1] + hv.z * w2r[h + 2] + hv.w * w2r[h + 3];
            }
            pf1[q] = pts_sh[q][(8 + i8) * 8 + j8] + acc;
            pf_sh[q][(8 + i8) * 8 + j8] = pf1[q];
        }
        if (i8 == 0) {
            #pragma unroll
            for (int q = 0; q < 2; ++q) {
                float acc = b2r;
                #pragma unroll
                for (int h = 0; h < 32; h += 4) {
                    const float4 hv = *(const float4*)&hid_sh[q][16 * HST + h];
                    acc += hv.x * w2r[h] + hv.y * w2r[h + 1] + hv.z * w2r[h + 2] + hv.w * w2r[h + 3];
                }
                pf2[q] = pts_sh[q][16 * 8 + j8] + acc;
                pf_sh[q][16 * 8 + j8] = pf2[q];
            }
        }
        __syncthreads();

        // ===== x_pred butterfly (Wm[0]=0, rest 1/16)
        float xp[2];
        #pragma unroll
        for (int q = 0; q < 2; ++q) {
            float part = ((i8 == 0) ? pf2[q] : pf0[q]) + pf1[q];
            part += __shfl_xor(part, 8);
            part += __shfl_xor(part, 16);
            part += __shfl_xor(part, 32);
            xp[q] = part * 0.0625f;
            if (i8 == 0) xp_sh[q][j8] = xp[q];
        }

        // ===== y_pts = pts_f Hm^T  (all reads before any pf_sh overwrite)
        float yv0[2], yv16[2] = {0.0f, 0.0f};
        #pragma unroll
        for (int q = 0; q < 2; ++q) {
            const float4 pa = *(const float4*)&pf_sh[q][sy * 8];
            const float4 pb = *(const float4*)&pf_sh[q][sy * 8 + 4];
            yv0[q] = pa.x * hmr[0] + pa.y * hmr[1] + pa.z * hmr[2] + pa.w * hmr[3]
                   + pb.x * hmr[4] + pb.y * hmr[5] + pb.z * hmr[6] + pb.w * hmr[7];
            if (sy == 0) {
                const float4 qa = *(const float4*)&pf_sh[q][16 * 8];
                const float4 qbv = *(const float4*)&pf_sh[q][16 * 8 + 4];
                yv16[q] = qa.x * hmr[0] + qa.y * hmr[1] + qa.z * hmr[2] + qa.w * hmr[3]
                        + qbv.x * hmr[4] + qbv.y * hmr[5] + qbv.z * hmr[6] + qbv.w * hmr[7];
            }
        }
        float ypredv[2];
        #pragma unroll
        for (int q = 0; q < 2; ++q) {
            float py = (sy == 0) ? yv16[q] : yv0[q];
            py += __shfl_xor(py, 4);
            py += __shfl_xor(py, 8);
            py += __shfl_xor(py, 16);
            py += __shfl_xor(py, 32);
            ypredv[q] = py * 0.0625f;
            if (lane < 4) ypred_sh[q][lane] = ypredv[q];
        }
        // dy -> LDS ; dx -> pf_sh in place (wave-ordered after reads above)
        #pragma unroll
        for (int q = 0; q < 2; ++q) {
            yp_sh[q][sy * 4 + m4] = yv0[q] - ypredv[q];
            if (sy == 0) yp_sh[q][16 * 4 + m4] = yv16[q] - ypredv[q];
            pf_sh[q][i8 * 8 + j8]       = pf0[q] - xp[q];
            pf_sh[q][(8 + i8) * 8 + j8] = pf1[q] - xp[q];
            if (i8 == 0) pf_sh[q][16 * 8 + j8] = pf2[q] - xp[q];
        }
        __syncthreads();

        // ===== P_pred (all lanes, per q)
        float Ppred[2];
        #pragma unroll
        for (int q = 0; q < 2; ++q) {
            float pp = 0.0f;
            #pragma unroll
            for (int s = 1; s < 17; ++s)
                pp += pf_sh[q][s * 8 + i8] * pf_sh[q][s * 8 + j8];
            pp *= 0.0625f;
            pp += 2.0f * pf_sh[q][i8] * pf_sh[q][j8];
            Ppred[q] = pp + ((i8 == j8) ? (qdiag + 1e-4f) : 0.0f);
        }
        // ===== Pxy (all 64 lanes: 2 batches x 32)
        {
            float acc = 0.0f;
            #pragma unroll
            for (int s = 1; s < 17; ++s)
                acc += pf_sh[qP][s * 8 + iiP] * yp_sh[qP][s * 4 + mmP];
            Pxy_sh[qP][idxP] = acc * 0.0625f + 2.0f * pf_sh[qP][iiP] * yp_sh[qP][mmP];
        }
        // ===== Sy (lanes 0..31: 2 batches x 16)
        float syv = 0.0f;
        if (lane < 32) {
            float acc = 0.0f;
            #pragma unroll
            for (int s = 1; s < 17; ++s)
                acc += yp_sh[qS][s * 4 + syS] * yp_sh[qS][s * 4 + m4S];
            syv = acc * 0.0625f + 2.0f * yp_sh[qS][syS] * yp_sh[qS][m4S]
                + ((syS == m4S) ? rdiagS : 0.0f);
            Sy_sh[qS][idx16] = syv;
        }

        // ===== chol4(Sy) + r_e (lanes 0..31, two groups)
        float l4v = syv;
        float re = 0.0f;
        #pragma unroll
        for (int j = 0; j < 4; ++j) {
            float dj = __shfl(l4v, gbase + j * 5);
            float sq = sqrtf(dj);
            float rv = fast_rcp(sq);
            re += __logf(sq);
            if (lane < 32 && m4S == j) l4v = (syS == j) ? sq : l4v * rv;
            float ci = __shfl(l4v, gbase + syS * 4 + j);
            float cj = __shfl(l4v, gbase + m4S * 4 + j);
            if (lane < 32 && syS > j && m4S > j) l4v -= ci * cj;
        }
        if (lane < 32) L4_sh[qS][idx16] = l4v;

        // ===== q_e = 0.5 slogdet(P_pred) via chol8, both batches interleaved
        float ap0 = Ppred[0], ap1 = Ppred[1];
        float qe0 = 0.0f, qe1 = 0.0f;
        #pragma unroll
        for (int j = 0; j < 8; ++j) {
            float d0 = __shfl(ap0, j * 9), d1 = __shfl(ap1, j * 9);
            float s0 = sqrtf(d0),          s1 = sqrtf(d1);
            qe0 += __logf(s0);             qe1 += __logf(s1);
            float r0 = fast_rcp(s0),       r1 = fast_rcp(s1);
            if (j8 == j) { ap0 = (i8 == j) ? s0 : ap0 * r0; ap1 = (i8 == j) ? s1 : ap1 * r1; }
            float ci0 = __shfl(ap0, i8 * 8 + j), ci1 = __shfl(ap1, i8 * 8 + j);
            float cj0 = __shfl(ap0, j8 * 8 + j), cj1 = __shfl(ap1, j8 * 8 + j);
            if (i8 > j && j8 > j) { ap0 -= ci0 * cj0; ap1 -= ci1 * cj1; }
        }
        __syncthreads();

        // ===== K = Pxy Sy^{-1}: tri-solves (lanes 0..15: 2 batches x 8 rows)
        if (lane < 16) {
            const float p0  = Pxy_sh[qK][rowK * 4 + 0];
            const float p1  = Pxy_sh[qK][rowK * 4 + 1];
            const float p2v = Pxy_sh[qK][rowK * 4 + 2];
            const float p3  = Pxy_sh[qK][rowK * 4 + 3];
            const float L00 = L4_sh[qK][0],  L10 = L4_sh[qK][4],  L11 = L4_sh[qK][5];
            const float L20 = L4_sh[qK][8],  L21 = L4_sh[qK][9],  L22 = L4_sh[qK][10];
            const float L30 = L4_sh[qK][12], L31 = L4_sh[qK][13], L32 = L4_sh[qK][14], L33 = L4_sh[qK][15];
            const float r0 = fast_rcp(L00), r1 = fast_rcp(L11);
            const float r2 = fast_rcp(L22), r3 = fast_rcp(L33);
            const float w0 = p0 * r0;
            const float w1 = (p1 - L10 * w0) * r1;
            const float w2 = (p2v - L20 * w0 - L21 * w1) * r2;
            const float w3 = (p3 - L30 * w0 - L31 * w1 - L32 * w2) * r3;
            const float k3 = w3 * r3;
            const float k2 = (w2 - L32 * k3) * r2;
            const float k1 = (w1 - L21 * k2 - L31 * k3) * r1;
            const float k0 = (w0 - L10 * k1 - L20 * k2 - L30 * k3) * r0;
            K_sh[qK][rowK * 4 + 0] = k0;
            K_sh[qK][rowK * 4 + 1] = k1;
            K_sh[qK][rowK * 4 + 2] = k2;
            K_sh[qK][rowK * 4 + 3] = k3;
        }
        __syncthreads();

        // ===== T1 = K * Sy (all 64 lanes: 2 batches x 32)
        T1_sh[qP][idxP] = K_sh[qP][iiP * 4 + 0] * Sy_sh[qP][0 + mmP]
                        + K_sh[qP][iiP * 4 + 1] * Sy_sh[qP][4 + mmP]
                        + K_sh[qP][iiP * 4 + 2] * Sy_sh[qP][8 + mmP]
                        + K_sh[qP][iiP * 4 + 3] * Sy_sh[qP][12 + mmP];
        __syncthreads();

        // ===== P_new = sym(Ppred - T1 K^T) + 1e-4 I, per q
        #pragma unroll
        for (int q = 0; q < 2; ++q) {
            float m_ = Ppred[q] - (T1_sh[q][i8 * 4 + 0] * K_sh[q][j8 * 4 + 0]
                                 + T1_sh[q][i8 * 4 + 1] * K_sh[q][j8 * 4 + 1]
                                 + T1_sh[q][i8 * 4 + 2] * K_sh[q][j8 * 4 + 2]
                                 + T1_sh[q][i8 * 4 + 3] * K_sh[q][j8 * 4 + 3]);
            float mT = __shfl(m_, j8 * 8 + i8);
            P[q] = 0.5f * (m_ + mT) + ((i8 == j8) ? 1e-4f : 0.0f);
            out[Pb[q] + (size_t)t * 64 + lane] = P[q];
        }

        // ===== x_new (lanes 0..15: 2 batches x 8)
        if (lane < 16) {
            const float in0 = y_sh[qK][t * 4 + 0] - ypred_sh[qK][0];
            const float in1 = y_sh[qK][t * 4 + 1] - ypred_sh[qK][1];
            const float in2 = y_sh[qK][t * 4 + 2] - ypred_sh[qK][2];
            const float in3 = y_sh[qK][t * 4 + 3] - ypred_sh[qK][3];
            const float xn = xp_sh[qK][rowK]
                + K_sh[qK][rowK * 4 + 0] * in0 + K_sh[qK][rowK * 4 + 1] * in1
                + K_sh[qK][rowK * 4 + 2] * in2 + K_sh[qK][rowK * 4 + 3] * in3;
            x_sh[qK][rowK] = xn;
            out[Xb[qK] + (size_t)t * 8 + rowK] = xn;
        }

        // ===== entropies: lane 0 holds batch0 re, lane 16 holds batch1 re
        if (lane == 0)  { out[qb[0] + t] = qe0; out[rb[0] + t] = re; }
        if (lane == 16) { out[qb[1] + t] = qe1; out[rb[1] + t] = re; }
        __syncthreads();
    }
}

extern "C" void kernel_launch(void* const* d_in, const int* in_sizes, int n_in,
                              void* d_out, int out_size, void* d_ws, size_t ws_size,
                              hipStream_t stream) {
    (void)in_sizes; (void)n_in; (void)out_size; (void)d_ws; (void)ws_size;
    const float* X0 = (const float*)d_in[0];
    const float* U  = (const float*)d_in[1];
    const float* Y  = (const float*)d_in[2];
    const float* W1 = (const float*)d_in[3];
    const float* B1 = (const float*)d_in[4];
    const float* W2 = (const float*)d_in[5];
    const float* B2 = (const float*)d_in[6];
    const float* HM = (const float*)d_in[7];
    const float* LQ = (const float*)d_in[8];
    const float* LR = (const float*)d_in[9];
    const float* LP0 = (const float*)d_in[10];
    float* out = (float*)d_out;
    ukf_kernel<<<dim3(B_LEN / 2), dim3(64), 0, stream>>>(X0, U, Y, W1, B1, W2, B2,
                                                         HM, LQ, LR, LP0, out);
}

// Round 3
// 982.123 us; speedup vs baseline: 2.2970x; 2.2970x over previous
//
#include <hip/hip_runtime.h>
#include <math.h>

#define B_LEN 1024
#define T_LEN 256
#define HST 36   // hid_sh leading stride: (s*36+h)/4 %32 distinct over s -> conflict-free float4

__device__ __forceinline__ float fast_rcp(float x) { return __builtin_amdgcn_rcpf(x); }
__device__ __forceinline__ float fast_rsq(float x) { return __builtin_amdgcn_rsqf(x); }
__device__ __forceinline__ float fast_tanh(float x) {
    float e = __expf(2.0f * x);
    return 1.0f - 2.0f * fast_rcp(e + 1.0f);
}
__device__ __forceinline__ float softplus_f(float x) {
    return (x > 20.0f) ? x : log1pf(expf(x));
}

// One batch per 128-thread block = 2 waves. 2048 waves total -> 2 waves/SIMD.
// wave0: sequential state owner (P reg, chol8 sigma, chol4, K, T1, P_new, x_new, re)
// wave1: y-side (y_pts, ypred, dy), Sy, Pxy, and the qe slogdet-chol8 overlapped
//        with wave0's measurement update. Layer1/layer2 split across both waves.
__global__ __launch_bounds__(128)
void ukf_kernel(const float* __restrict__ X0, const float* __restrict__ U,
                const float* __restrict__ Y,  const float* __restrict__ W1,
                const float* __restrict__ B1, const float* __restrict__ W2,
                const float* __restrict__ B2, const float* __restrict__ HM,
                const float* __restrict__ LQ, const float* __restrict__ LR,
                const float* __restrict__ LP0, float* __restrict__ out)
{
    const int tid  = threadIdx.x;
    const int wid  = tid >> 6;        // 0 or 1
    const int lane = tid & 63;
    const int b    = blockIdx.x;
    const int i8   = lane >> 3;
    const int j8   = lane & 7;
    const int h32  = lane & 31;
    const int p4   = tid >> 5;        // 0..3 across the block (layer1 sigma group)
    const int m4   = lane & 3;
    const int sy   = lane >> 2;
    const int s2   = tid >> 3;        // 0..15 (layer2 sigma index)
    const int d2   = tid & 7;         // == j8

    __shared__ float u_sh[T_LEN * 2];
    __shared__ float y_sh[T_LEN * 4];
    __shared__ __align__(16) float pts_sh[17 * 8];
    __shared__ __align__(16) float hid_sh[17 * HST];
    __shared__ __align__(16) float pf_sh[17 * 8];
    __shared__ __align__(16) float dx_sh[17 * 8];
    __shared__ __align__(16) float yp_sh[17 * 4];
    __shared__ float x_sh[8];
    __shared__ float xp_sh[8];
    __shared__ float ypred_sh[4];
    __shared__ float Sy_sh[16];
    __shared__ float L4_sh[16];
    __shared__ float Pxy_sh[32];
    __shared__ float K_sh[32];
    __shared__ float T1_sh[32];
    __shared__ float Pp_sh[64];

    // ---- one-time staging (both waves) ----
    for (int k = tid; k < T_LEN * 2; k += 128) u_sh[k] = U[(size_t)b * (T_LEN * 2) + k];
    for (int k = tid; k < T_LEN * 4; k += 128) y_sh[k] = Y[(size_t)b * (T_LEN * 4) + k];

    float w1r[10];
    #pragma unroll
    for (int d = 0; d < 10; ++d) w1r[d] = W1[d * 32 + h32];
    const float b1r = B1[h32];
    float w2r[32];
    #pragma unroll
    for (int h = 0; h < 32; ++h) w2r[h] = W2[h * 8 + d2];
    const float b2r = B2[d2];
    float hmr[8];                              // used by wave1
    #pragma unroll
    for (int d = 0; d < 8; ++d) hmr[d] = HM[m4 * 8 + d];

    const float qdiag = softplus_f(LQ[i8]);
    const float rdiag = softplus_f(LR[m4]);

    const size_t Xbase = (size_t)b * T_LEN * 8;
    const size_t Pbase = (size_t)B_LEN * T_LEN * 8  + (size_t)b * T_LEN * 64;
    const size_t qbase = (size_t)B_LEN * T_LEN * 72 + (size_t)b * T_LEN;
    const size_t rbase = (size_t)B_LEN * T_LEN * 73 + (size_t)b * T_LEN;

    // ---- initial state / t=0 outputs ----
    float P = (i8 == j8) ? softplus_f(LP0[i8]) : 0.0f;   // wave0 owns P
    if (tid < 8) x_sh[tid] = X0[b * 8 + tid];
    if (wid == 0) {
        if (lane < 8) out[Xbase + lane] = X0[b * 8 + lane];
        out[Pbase + lane] = P;
        if (lane == 0) { out[qbase] = 0.0f; out[rbase] = 0.0f; }
    }
    __syncthreads();

    for (int t = 1; t < T_LEN; ++t) {
        // ===== [w0] chol8(8P + jitter) in-register, and sigma points -> LDS ====
        if (wid == 0) {
            float a = 8.0f * P + ((i8 == j8) ? 1e-4f : 0.0f);
            #pragma unroll
            for (int j = 0; j < 8; ++j) {
                float dj = __shfl(a, j * 9);
                float rv = fast_rsq(dj);
                if (j8 == j) a = (i8 == j) ? dj * rv : a * rv;
                float ci = __shfl(a, i8 * 8 + j);
                float cj = __shfl(a, j8 * 8 + j);
                if (i8 > j && j8 > j) a -= ci * cj;
            }
            const float Lx = (j8 <= i8) ? a : 0.0f;
            const float xi = x_sh[i8];
            if (j8 == 0) pts_sh[i8] = xi;
            pts_sh[(1 + j8) * 8 + i8] = xi + Lx;
            pts_sh[(9 + j8) * 8 + i8] = xi - Lx;
        }
        __syncthreads();   // b1: pts ready

        // ===== [both] layer 1: hidden = tanh([pts;u] W1 + b1) =================
        {
            const float u0 = u_sh[(t - 1) * 2 + 0];
            const float u1 = u_sh[(t - 1) * 2 + 1];
            const float ub = b1r + u0 * w1r[8] + u1 * w1r[9];
            #pragma unroll
            for (int k = 0; k < 5; ++k) {
                int s = 4 * k + p4;
                if (s < 17) {
                    const float4 pa = *(const float4*)&pts_sh[s * 8];
                    const float4 pb = *(const float4*)&pts_sh[s * 8 + 4];
                    float acc = ub
                        + pa.x * w1r[0] + pa.y * w1r[1] + pa.z * w1r[2] + pa.w * w1r[3]
                        + pb.x * w1r[4] + pb.y * w1r[5] + pb.z * w1r[6] + pb.w * w1r[7];
                    hid_sh[s * HST + h32] = fast_tanh(acc);
                }
            }
        }
        __syncthreads();   // b2: hid ready

        // ===== [both] layer 2: pf = pts + hid W2 + b2 (s2=tid>>3; w0 also s=16)
        {
            float acc = b2r;
            #pragma unroll
            for (int h = 0; h < 32; h += 4) {
                const float4 hv = *(const float4*)&hid_sh[s2 * HST + h];
                acc += hv.x * w2r[h] + hv.y * w2r[h + 1] + hv.z * w2r[h + 2] + hv.w * w2r[h + 3];
            }
            pf_sh[s2 * 8 + d2] = pts_sh[s2 * 8 + d2] + acc;
            if (tid < 8) {
                float a16 = b2r;
                #pragma unroll
                for (int h = 0; h < 32; h += 4) {
                    const float4 hv = *(const float4*)&hid_sh[16 * HST + h];
                    a16 += hv.x * w2r[h] + hv.y * w2r[h + 1] + hv.z * w2r[h + 2] + hv.w * w2r[h + 3];
                }
                pf_sh[16 * 8 + tid] = pts_sh[16 * 8 + tid] + a16;
            }
        }
        __syncthreads();   // b3: pf ready

        // ===== [w0] x_pred + dx ; [w1] y_pts + ypred + dy =====================
        if (wid == 0) {
            const float v0   = pf_sh[i8 * 8 + j8];          // s = i8
            const float v1   = pf_sh[(8 + i8) * 8 + j8];    // s = 8+i8
            const float pf16 = (i8 == 0) ? pf_sh[16 * 8 + j8] : 0.0f;
            float part = ((i8 == 0) ? pf16 : v0) + v1;      // s=16 replaces s=0
            part += __shfl_xor(part, 8);
            part += __shfl_xor(part, 16);
            part += __shfl_xor(part, 32);
            const float xp = part * 0.0625f;
            if (i8 == 0) xp_sh[j8] = xp;
            dx_sh[i8 * 8 + j8]       = v0 - xp;
            dx_sh[(8 + i8) * 8 + j8] = v1 - xp;
            if (i8 == 0) dx_sh[16 * 8 + j8] = pf16 - xp;
        } else {
            float yv0, yv16 = 0.0f;
            {
                const float4 pa = *(const float4*)&pf_sh[sy * 8];
                const float4 pb = *(const float4*)&pf_sh[sy * 8 + 4];
                yv0 = pa.x * hmr[0] + pa.y * hmr[1] + pa.z * hmr[2] + pa.w * hmr[3]
                    + pb.x * hmr[4] + pb.y * hmr[5] + pb.z * hmr[6] + pb.w * hmr[7];
            }
            if (sy == 0) {
                const float4 pa = *(const float4*)&pf_sh[16 * 8];
                const float4 pb = *(const float4*)&pf_sh[16 * 8 + 4];
                yv16 = pa.x * hmr[0] + pa.y * hmr[1] + pa.z * hmr[2] + pa.w * hmr[3]
                     + pb.x * hmr[4] + pb.y * hmr[5] + pb.z * hmr[6] + pb.w * hmr[7];
            }
            float py = (sy == 0) ? yv16 : yv0;
            py += __shfl_xor(py, 4);
            py += __shfl_xor(py, 8);
            py += __shfl_xor(py, 16);
            py += __shfl_xor(py, 32);
            const float ypred = py * 0.0625f;
            if (lane < 4) ypred_sh[lane] = ypred;
            yp_sh[sy * 4 + m4] = yv0 - ypred;
            if (sy == 0) yp_sh[16 * 4 + m4] = yv16 - ypred;
        }
        __syncthreads();   // b4: dx, dy, xp, ypred ready

        // ===== [w0] P_pred -> reg + Pp_sh ; [w1] Sy + Pxy =====================
        float Ppred = 0.0f;
        if (wid == 0) {
            float pp = 0.0f;
            #pragma unroll
            for (int s = 1; s < 17; ++s)
                pp += dx_sh[s * 8 + i8] * dx_sh[s * 8 + j8];
            pp *= 0.0625f;
            pp += 2.0f * dx_sh[i8] * dx_sh[j8];               // Wc[0] = 2
            Ppred = pp + ((i8 == j8) ? (qdiag + 1e-4f) : 0.0f);
            Pp_sh[lane] = Ppred;
        } else {
            if (lane < 16) {
                float acc = 0.0f;
                #pragma unroll
                for (int s = 1; s < 17; ++s)
                    acc += yp_sh[s * 4 + sy] * yp_sh[s * 4 + m4];
                Sy_sh[lane] = acc * 0.0625f + 2.0f * yp_sh[sy] * yp_sh[m4]
                            + ((sy == m4) ? rdiag : 0.0f);
            } else if (lane < 48) {
                const int idx = lane - 16;
                const int ii = idx >> 2, mm = idx & 3;
                float acc = 0.0f;
                #pragma unroll
                for (int s = 1; s < 17; ++s)
                    acc += dx_sh[s * 8 + ii] * yp_sh[s * 4 + mm];
                Pxy_sh[idx] = acc * 0.0625f + 2.0f * dx_sh[ii] * yp_sh[mm];
            }
        }
        __syncthreads();   // b5: Ppred/Sy/Pxy ready

        if (wid == 0) {
            // ===== chol4(Sy) + r_e (lanes 0..15) ==============================
            float l4v = (lane < 16) ? Sy_sh[lane] : 0.0f;
            float re = 0.0f;
            #pragma unroll
            for (int j = 0; j < 4; ++j) {
                float dj = __shfl(l4v, j * 5);
                float rv = fast_rsq(dj);
                re += 0.5f * __logf(dj);
                if (lane < 16 && m4 == j) l4v = (sy == j) ? dj * rv : l4v * rv;
                float ci = __shfl(l4v, (sy * 4 + j) & 63);
                float cj = __shfl(l4v, (m4 * 4 + j) & 63);
                if (lane < 16 && sy > j && m4 > j) l4v -= ci * cj;
            }
            if (lane < 16) L4_sh[lane] = l4v;

            // ===== K = Pxy Sy^{-1} tri-solves (lanes 0..7) ====================
            if (lane < 8) {
                const float p0  = Pxy_sh[lane * 4 + 0];
                const float p1  = Pxy_sh[lane * 4 + 1];
                const float p2v = Pxy_sh[lane * 4 + 2];
                const float p3  = Pxy_sh[lane * 4 + 3];
                const float L00 = L4_sh[0],  L10 = L4_sh[4],  L11 = L4_sh[5];
                const float L20 = L4_sh[8],  L21 = L4_sh[9],  L22 = L4_sh[10];
                const float L30 = L4_sh[12], L31 = L4_sh[13], L32 = L4_sh[14], L33 = L4_sh[15];
                const float r0 = fast_rcp(L00), r1 = fast_rcp(L11);
                const float r2 = fast_rcp(L22), r3 = fast_rcp(L33);
                const float w0_ = p0 * r0;
                const float w1_ = (p1 - L10 * w0_) * r1;
                const float w2_ = (p2v - L20 * w0_ - L21 * w1_) * r2;
                const float w3_ = (p3 - L30 * w0_ - L31 * w1_ - L32 * w2_) * r3;
                const float k3 = w3_ * r3;
                const float k2 = (w2_ - L32 * k3) * r2;
                const float k1 = (w1_ - L21 * k2 - L31 * k3) * r1;
                const float k0 = (w0_ - L10 * k1 - L20 * k2 - L30 * k3) * r0;
                K_sh[lane * 4 + 0] = k0;
                K_sh[lane * 4 + 1] = k1;
                K_sh[lane * 4 + 2] = k2;
                K_sh[lane * 4 + 3] = k3;
            }
            // ===== T1 = K * Sy (lanes 0..31), intra-wave through LDS ==========
            if (lane < 32) {
                const int ii = lane >> 2, aa = lane & 3;
                T1_sh[lane] = K_sh[ii * 4 + 0] * Sy_sh[0 + aa]
                            + K_sh[ii * 4 + 1] * Sy_sh[4 + aa]
                            + K_sh[ii * 4 + 2] * Sy_sh[8 + aa]
                            + K_sh[ii * 4 + 3] * Sy_sh[12 + aa];
            }
            // ===== P_new = sym(Ppred - T1 K^T) + 1e-4 I =======================
            float m_ = Ppred - (T1_sh[i8 * 4 + 0] * K_sh[j8 * 4 + 0]
                              + T1_sh[i8 * 4 + 1] * K_sh[j8 * 4 + 1]
                              + T1_sh[i8 * 4 + 2] * K_sh[j8 * 4 + 2]
                              + T1_sh[i8 * 4 + 3] * K_sh[j8 * 4 + 3]);
            float mT = __shfl(m_, j8 * 8 + i8);
            P = 0.5f * (m_ + mT) + ((i8 == j8) ? 1e-4f : 0.0f);
            out[Pbase + (size_t)t * 64 + lane] = P;

            // ===== x_new (lanes 0..7) =========================================
            if (lane < 8) {
                const float in0 = y_sh[t * 4 + 0] - ypred_sh[0];
                const float in1 = y_sh[t * 4 + 1] - ypred_sh[1];
                const float in2 = y_sh[t * 4 + 2] - ypred_sh[2];
                const float in3 = y_sh[t * 4 + 3] - ypred_sh[3];
                const float xn = xp_sh[lane]
                    + K_sh[lane * 4 + 0] * in0 + K_sh[lane * 4 + 1] * in1
                    + K_sh[lane * 4 + 2] * in2 + K_sh[lane * 4 + 3] * in3;
                x_sh[lane] = xn;
                out[Xbase + (size_t)t * 8 + lane] = xn;
            }
            if (lane == 0) out[rbase + t] = re;
        } else {
            // ===== [w1] q_e = 0.5 slogdet(P_pred) via chol8 (overlapped) ======
            float ap = Pp_sh[lane];
            float qe = 0.0f;
            #pragma unroll
            for (int j = 0; j < 8; ++j) {
                float dj = __shfl(ap, j * 9);
                float rv = fast_rsq(dj);
                qe += 0.5f * __logf(dj);
                if (j8 == j) ap = (i8 == j) ? dj * rv : ap * rv;
                float ci = __shfl(ap, i8 * 8 + j);
                float cj = __shfl(ap, j8 * 8 + j);
                if (i8 > j && j8 > j) ap -= ci * cj;
            }
            if (lane == 0) out[qbase + t] = qe;
        }
        // next iteration's b1 doubles as the end-of-step barrier
    }
}

extern "C" void kernel_launch(void* const* d_in, const int* in_sizes, int n_in,
                              void* d_out, int out_size, void* d_ws, size_t ws_size,
                              hipStream_t stream) {
    (void)in_sizes; (void)n_in; (void)out_size; (void)d_ws; (void)ws_size;
    const float* X0 = (const float*)d_in[0];
    const float* U  = (const float*)d_in[1];
    const float* Y  = (const float*)d_in[2];
    const float* W1 = (const float*)d_in[3];
    const float* B1 = (const float*)d_in[4];
    const float* W2 = (const float*)d_in[5];
    const float* B2 = (const float*)d_in[6];
    const float* HM = (const float*)d_in[7];
    const float* LQ = (const float*)d_in[8];
    const float* LR = (const float*)d_in[9];
    const float* LP0 = (const float*)d_in[10];
    float* out = (float*)d_out;
    ukf_kernel<<<dim3(B_LEN), dim3(128), 0, stream>>>(X0, U, Y, W1, B1, W2, B2,
                                                      HM, LQ, LR, LP0, out);
}